// Round 1
// baseline (958.686 us; speedup 1.0000x reference)
//
#include <hip/hip_runtime.h>
#include <hip/hip_bf16.h>
#include <math.h>

// Problem constants
#define NN   2048      // N nodes
#define EE   8192      // E edges
#define CN   256
#define CE   256
#define MN   16384
#define ME   65536
#define KK   1024      // K_KEEP

// Output layout (float element offsets)
#define OUT_XN   ((size_t)0)                 // 1024*256
#define OUT_L0   ((size_t)262144)            // 1024*1024
#define OUT_XE   ((size_t)1310720)           // 8192*256
#define OUT_L1   ((size_t)3407872)           // 8192*8192
#define OUT_PM   ((size_t)70516736)          // 1024*8192
#define OUT_XN0  ((size_t)78905344)          // 1024*256
#define OUT_XE0  ((size_t)79167488)          // 8192*256

// Workspace layout (element offsets from base)
#define WS_T1N    0        // float[2048]
#define WS_SLINN  2048     // float[2048]
#define WS_T1E    4096     // float[8192]
#define WS_SLINE  12288    // float[8192]
#define WS_SCN    20480    // float[2048]
#define WS_SCE    22528    // float[8192]
#define WS_JOINT  30720    // float[2048]
#define WS_AGGN   32768    // float[2048]
#define WS_AGGE   34816    // float[8192]
#define WS_LAM    43008    // float[1]
#define WS_IDXK   43520    // int[1024]
#define WS_RANK   44544    // int[2048]
#define WS_DEG    46592    // int[1024]
#define WS_OFFS   47616    // int[1025]
#define WS_CUR    48768    // int[1024]
#define WS_ADJO   49792    // int[16384]  other-endpoint rank
#define WS_ADJE   66176    // int[16384]  (edge<<1)|sign_is_plus
#define WS_END    82560
#define WS_ZERO_BYTES ((size_t)WS_END * 4)

// ---------------------------------------------------------------- row dots
// one wave per row; rows [0,NN) = nodes, [NN, NN+EE) = edges
__global__ void k_rowdots(const float* __restrict__ xn, const float* __restrict__ xe,
                          const float* __restrict__ Wn0, const float* __restrict__ Wn1,
                          const float* __restrict__ We0, const float* __restrict__ We1,
                          float* __restrict__ wsf) {
    int w = (blockIdx.x * blockDim.x + threadIdx.x) >> 6;
    int lane = threadIdx.x & 63;
    if (w >= NN + EE) return;
    const float *x, *W0, *W1;
    float *t1, *sl;
    int r;
    if (w < NN) { r = w;      x = xn + (size_t)r * CN; W0 = Wn0; W1 = Wn1; t1 = wsf + WS_T1N; sl = wsf + WS_SLINN; }
    else        { r = w - NN; x = xe + (size_t)r * CE; W0 = We0; W1 = We1; t1 = wsf + WS_T1E; sl = wsf + WS_SLINE; }
    float4 xv = ((const float4*)x)[lane];
    float4 w0 = ((const float4*)W0)[lane];
    float4 w1 = ((const float4*)W1)[lane];
    float d0 = xv.x*w0.x + xv.y*w0.y + xv.z*w0.z + xv.w*w0.w;
    float d1 = xv.x*w1.x + xv.y*w1.y + xv.z*w1.z + xv.w*w1.w;
    #pragma unroll
    for (int o = 32; o > 0; o >>= 1) { d0 += __shfl_down(d0, o, 64); d1 += __shfl_down(d1, o, 64); }
    if (lane == 0) { t1[r] = d1; sl[r] = d0 + d1; }
}

// ------------------------------------------------------- conv-edge scatter
__global__ void k_agg(const int* __restrict__ ein, const float* __restrict__ ewn,
                      const int* __restrict__ eie, const float* __restrict__ ewe,
                      float* __restrict__ wsf) {
    int i = blockIdx.x * blockDim.x + threadIdx.x;
    if (i < MN) {
        int s = ein[i], d = ein[MN + i];
        atomicAdd(wsf + WS_AGGN + d, ewn[i] * wsf[WS_T1N + s]);
    }
    if (i < ME) {
        int s = eie[i], d = eie[ME + i];
        atomicAdd(wsf + WS_AGGE + d, ewe[i] * wsf[WS_T1E + s]);
    }
}

// ---------------------------------------------------------------- sigmoid
__global__ void k_score(const float* __restrict__ bn, const float* __restrict__ be,
                        float* __restrict__ wsf) {
    int i = blockIdx.x * blockDim.x + threadIdx.x;
    if (i < NN) {
        float z = wsf[WS_SLINN + i] - wsf[WS_AGGN + i] + bn[0];
        float s = 1.0f / (1.0f + expf(-z));
        wsf[WS_SCN + i] = s;
        wsf[WS_JOINT + i] = s;
    } else if (i < NN + EE) {
        int j = i - NN;
        float z = wsf[WS_SLINE + j] - wsf[WS_AGGE + j] + be[0];
        wsf[WS_SCE + j] = 1.0f / (1.0f + expf(-z));
    }
}

__global__ void k_joint(const int* __restrict__ ei, float* __restrict__ wsf) {
    int e = blockIdx.x * blockDim.x + threadIdx.x;
    if (e >= EE) return;
    float v = 0.125f * wsf[WS_SCE + e];
    atomicAdd(wsf + WS_JOINT + ei[e], v);
    atomicAdd(wsf + WS_JOINT + ei[EE + e], v);
}

// ------------------------------------------------------- top-K (single block)
__global__ __launch_bounds__(1024) void k_topk(float* __restrict__ wsf, int* __restrict__ wsi) {
    __shared__ unsigned long long keys[2048];
    __shared__ unsigned ids[1024];
    int t = threadIdx.x;
    wsi[WS_RANK + t] = -1;
    wsi[WS_RANK + t + 1024] = -1;
    for (int i = t; i < 2048; i += 1024) {
        float f = wsf[WS_JOINT + i];
        unsigned u = __float_as_uint(f);
        unsigned s = (u & 0x80000000u) ? ~u : (u | 0x80000000u);
        keys[i] = (((unsigned long long)(~s)) << 32) | (unsigned)i;  // asc sort => val desc, idx asc
    }
    __syncthreads();
    for (int k = 2; k <= 2048; k <<= 1) {
        for (int j = k >> 1; j >= 1; j >>= 1) {
            for (int i = t; i < 2048; i += 1024) {
                int ixj = i ^ j;
                if (ixj > i) {
                    bool up = ((i & k) == 0);
                    unsigned long long a = keys[i], b = keys[ixj];
                    if ((a > b) == up) { keys[i] = b; keys[ixj] = a; }
                }
            }
            __syncthreads();
        }
    }
    ids[t] = (unsigned)(keys[t] & 0xFFFFFFFFu);
    __syncthreads();
    for (int k = 2; k <= 1024; k <<= 1) {
        for (int j = k >> 1; j >= 1; j >>= 1) {
            int i = t, ixj = i ^ j;
            if (ixj > i) {
                bool up = ((i & k) == 0);
                unsigned a = ids[i], b = ids[ixj];
                if ((a > b) == up) { ids[i] = b; ids[ixj] = a; }
            }
            __syncthreads();
        }
    }
    wsi[WS_IDXK + t] = (int)ids[t];
    wsi[WS_RANK + (int)ids[t]] = t;
}

// ----------------------------- kept-edge pass: par_masked, L0 nnz, degrees
__global__ void k_build(const int* __restrict__ ei, int* __restrict__ wsi,
                        float* __restrict__ pm, float* __restrict__ L0) {
    int e = blockIdx.x * blockDim.x + threadIdx.x;
    if (e >= EE) return;
    int s = ei[e], d = ei[EE + e];
    int rs = wsi[WS_RANK + s], rd = wsi[WS_RANK + d];
    if (rs < 0 || rd < 0 || s == d) return;
    pm[(size_t)rs * EE + e] = -1.0f;
    pm[(size_t)rd * EE + e] =  1.0f;
    atomicAdd(wsi + WS_DEG + rs, 1);
    atomicAdd(wsi + WS_DEG + rd, 1);
    atomicAdd(&L0[(size_t)rs * KK + rs],  1.0f);
    atomicAdd(&L0[(size_t)rd * KK + rd],  1.0f);
    atomicAdd(&L0[(size_t)rs * KK + rd], -1.0f);
    atomicAdd(&L0[(size_t)rd * KK + rs], -1.0f);
}

// --------------------------------------------------------------- CSR scan
__global__ __launch_bounds__(1024) void k_scan(int* __restrict__ wsi) {
    __shared__ int s[1024];
    int t = threadIdx.x;
    int dg = wsi[WS_DEG + t];
    s[t] = dg;
    for (int off = 1; off < 1024; off <<= 1) {
        __syncthreads();
        int v = (t >= off) ? s[t - off] : 0;
        __syncthreads();
        s[t] += v;
    }
    __syncthreads();
    wsi[WS_OFFS + t] = s[t] - dg;
    wsi[WS_CUR  + t] = s[t] - dg;
    if (t == 1023) wsi[WS_OFFS + 1024] = s[1023];
}

__global__ void k_fill(const int* __restrict__ ei, int* __restrict__ wsi) {
    int e = blockIdx.x * blockDim.x + threadIdx.x;
    if (e >= EE) return;
    int s = ei[e], d = ei[EE + e];
    int rs = wsi[WS_RANK + s], rd = wsi[WS_RANK + d];
    if (rs < 0 || rd < 0 || s == d) return;
    int p = atomicAdd(wsi + WS_CUR + rs, 1);
    wsi[WS_ADJO + p] = rd;
    wsi[WS_ADJE + p] = (e << 1);        // sign -1 (src)
    int q = atomicAdd(wsi + WS_CUR + rd, 1);
    wsi[WS_ADJO + q] = rs;
    wsi[WS_ADJE + q] = (e << 1) | 1;    // sign +1 (dst)
}

// --------------------------------------------------- block reduce (16 waves)
__device__ __forceinline__ float block_reduce_sum(float val, float* red) {
    #pragma unroll
    for (int o = 32; o > 0; o >>= 1) val += __shfl_down(val, o, 64);
    int lane = threadIdx.x & 63, wid = threadIdx.x >> 6;
    if (lane == 0) red[wid] = val;
    __syncthreads();
    float r = 0.0f;
    if (threadIdx.x < 16) {
        r = red[threadIdx.x];
        #pragma unroll
        for (int o = 8; o > 0; o >>= 1) r += __shfl_down(r, o, 16);
        if (threadIdx.x == 0) red[0] = r;
    }
    __syncthreads();
    float out = red[0];
    __syncthreads();
    return out;
}

// ------------------------------------------- power iteration for lambda_max
#define ADJ_LDS 12288
__global__ __launch_bounds__(1024) void k_power(const int* __restrict__ wsi, float* __restrict__ lam) {
    __shared__ float v[1024];
    __shared__ float red[16];
    __shared__ int adjs[ADJ_LDS];
    int t = threadIdx.x;
    int d  = wsi[WS_DEG + t];
    int o0 = wsi[WS_OFFS + t];
    int total = wsi[WS_OFFS + 1024];
    int lim = total < ADJ_LDS ? total : ADJ_LDS;
    for (int i = t; i < lim; i += 1024) adjs[i] = wsi[WS_ADJO + i];
    // pseudo-random init (all-ones is in ker(L0)!)
    unsigned h = (unsigned)t * 2654435761u + 911u;
    h ^= h >> 15; h *= 2246822519u; h ^= h >> 13;
    v[t] = (float)(h & 0xFFFFu) * (1.0f / 65536.0f) - 0.5f;
    __syncthreads();
    const int T = 320;   // multiple of 8 -> last iter normalized
    for (int iter = 0; iter < T; ++iter) {
        float acc = 0.0f;
        for (int i = o0; i < o0 + d; ++i) {
            int a = (i < ADJ_LDS) ? adjs[i] : wsi[WS_ADJO + i];
            acc += v[a];
        }
        float y = (float)d * v[t] - acc;
        float scale;
        if ((iter & 7) == 7) {
            float n2 = block_reduce_sum(y * y, red);
            scale = (n2 > 0.0f) ? rsqrtf(n2) : 0.0f;
        } else {
            scale = 1.0f;
            __syncthreads();
        }
        v[t] = y * scale;
        __syncthreads();
    }
    // Rayleigh quotient with normalized v
    float acc = 0.0f;
    for (int i = o0; i < o0 + d; ++i) {
        int a = (i < ADJ_LDS) ? adjs[i] : wsi[WS_ADJO + i];
        acc += v[a];
    }
    float y = (float)d * v[t] - acc;
    float rq = block_reduce_sum(v[t] * y, red);
    if (t == 0) lam[0] = rq;
}

// --------------------------------------------------------------- L0 scale
__global__ void k_scaleL0(float* __restrict__ L0, const float* __restrict__ lam) {
    int i = blockIdx.x * blockDim.x + threadIdx.x;
    if (i >= KK * KK) return;
    L0[i] *= 2.0f / lam[0];
}

// ------------------------------------------------------------- L1 scatter
__global__ void k_L1(const int* __restrict__ wsi, const float* __restrict__ lam,
                     float* __restrict__ L1) {
    int r = blockIdx.x * blockDim.x + threadIdx.x;
    if (r >= KK) return;
    int o0 = wsi[WS_OFFS + r], o1 = wsi[WS_OFFS + r + 1];
    float sc = 2.0f / lam[0];
    for (int i = o0; i < o1; ++i) {
        int eiv = wsi[WS_ADJE + i];
        int e = eiv >> 1;
        float si = (eiv & 1) ? 1.0f : -1.0f;
        for (int j = o0; j < o1; ++j) {
            int ejv = wsi[WS_ADJE + j];
            int f = ejv >> 1;
            float sj = (ejv & 1) ? 1.0f : -1.0f;
            atomicAdd(&L1[(size_t)e * EE + f], si * sj * sc);
        }
    }
}

// --------------------------------------------------------- feature outputs
__global__ void k_gather_nodes(const float* __restrict__ xn, const float* __restrict__ xn0,
                               const float* __restrict__ wsf, const int* __restrict__ wsi,
                               float* __restrict__ out_xn, float* __restrict__ out_xn0) {
    int r = blockIdx.x, c = threadIdx.x;
    int src = wsi[WS_IDXK + r];
    float sc = wsf[WS_SCN + src];
    out_xn [(size_t)r * CN + c] = xn [(size_t)src * CN + c] * sc;
    out_xn0[(size_t)r * CN + c] = xn0[(size_t)src * CN + c];
}

__global__ void k_edges_out(const float* __restrict__ xe, const float* __restrict__ xe0,
                            const float* __restrict__ wsf, const int* __restrict__ wsi,
                            const int* __restrict__ ei,
                            float* __restrict__ out_xe, float* __restrict__ out_xe0) {
    int e = blockIdx.x, c = threadIdx.x;
    int s = ei[e], d = ei[EE + e];
    if (wsi[WS_RANK + s] < 0 || wsi[WS_RANK + d] < 0) return;  // row stays zero
    float sc = wsf[WS_SCE + e];
    out_xe [(size_t)e * CE + c] = xe [(size_t)e * CE + c] * sc;
    out_xe0[(size_t)e * CE + c] = xe0[(size_t)e * CE + c];
}

extern "C" void kernel_launch(void* const* d_in, const int* in_sizes, int n_in,
                              void* d_out, int out_size, void* d_ws, size_t ws_size,
                              hipStream_t stream) {
    const float* x_n  = (const float*)d_in[0];
    const int*   ei_n = (const int*)  d_in[1];
    const float* ew_n = (const float*)d_in[2];
    const float* x_e  = (const float*)d_in[3];
    const int*   ei_e = (const int*)  d_in[4];
    const float* ew_e = (const float*)d_in[5];
    const int*   ei   = (const int*)  d_in[6];
    const float* x_n0 = (const float*)d_in[9];
    const float* x_e0 = (const float*)d_in[10];
    const float* Wn0  = (const float*)d_in[11];
    const float* Wn1  = (const float*)d_in[12];
    const float* bn   = (const float*)d_in[13];
    const float* We0  = (const float*)d_in[14];
    const float* We1  = (const float*)d_in[15];
    const float* be   = (const float*)d_in[16];

    float* out = (float*)d_out;
    float* wsf = (float*)d_ws;
    int*   wsi = (int*)d_ws;

    hipMemsetAsync(d_out, 0, (size_t)out_size * sizeof(float), stream);
    hipMemsetAsync(d_ws, 0, WS_ZERO_BYTES, stream);

    k_rowdots<<<(NN + EE) / 4, 256, 0, stream>>>(x_n, x_e, Wn0, Wn1, We0, We1, wsf);
    k_agg<<<ME / 256, 256, 0, stream>>>(ei_n, ew_n, ei_e, ew_e, wsf);
    k_score<<<(NN + EE) / 256, 256, 0, stream>>>(bn, be, wsf);
    k_joint<<<EE / 256, 256, 0, stream>>>(ei, wsf);
    k_topk<<<1, 1024, 0, stream>>>(wsf, wsi);
    k_build<<<EE / 256, 256, 0, stream>>>(ei, wsi, out + OUT_PM, out + OUT_L0);
    k_scan<<<1, 1024, 0, stream>>>(wsi);
    k_fill<<<EE / 256, 256, 0, stream>>>(ei, wsi);
    k_power<<<1, 1024, 0, stream>>>(wsi, wsf + WS_LAM);
    k_scaleL0<<<(KK * KK) / 256, 256, 0, stream>>>(out + OUT_L0, wsf + WS_LAM);
    k_L1<<<KK / 256, 256, 0, stream>>>(wsi, wsf + WS_LAM, out + OUT_L1);
    k_gather_nodes<<<KK, 256, 0, stream>>>(x_n, x_n0, wsf, wsi, out + OUT_XN, out + OUT_XN0);
    k_edges_out<<<EE, 256, 0, stream>>>(x_e, x_e0, wsf, wsi, ei, out + OUT_XE, out + OUT_XE0);
}

// Round 2
// 596.509 us; speedup vs baseline: 1.6072x; 1.6072x over previous
//
#include <hip/hip_runtime.h>
#include <hip/hip_bf16.h>
#include <math.h>

// Problem constants
#define NN   2048      // N nodes
#define EE   8192      // E edges
#define CN   256
#define CE   256
#define MN   16384
#define ME   65536
#define KK   1024      // K_KEEP

// Output layout (float element offsets)
#define OUT_XN   ((size_t)0)                 // 1024*256
#define OUT_L0   ((size_t)262144)            // 1024*1024
#define OUT_XE   ((size_t)1310720)           // 8192*256
#define OUT_L1   ((size_t)3407872)           // 8192*8192
#define OUT_PM   ((size_t)70516736)          // 1024*8192
#define OUT_XN0  ((size_t)78905344)          // 1024*256
#define OUT_XE0  ((size_t)79167488)          // 8192*256

// Workspace layout (element offsets from base)
#define WS_T1N    0        // float[2048]
#define WS_SLINN  2048     // float[2048]
#define WS_T1E    4096     // float[8192]
#define WS_SLINE  12288    // float[8192]
#define WS_SCN    20480    // float[2048]
#define WS_SCE    22528    // float[8192]
#define WS_JOINT  30720    // float[2048]
#define WS_AGGN   32768    // float[2048]
#define WS_AGGE   34816    // float[8192]
#define WS_LAM    43008    // float[1]
#define WS_IDXK   43520    // int[1024]
#define WS_RANK   44544    // int[2048]
#define WS_DEG    46592    // int[1024]
#define WS_OFFS   47616    // int[1025]
#define WS_CUR    48768    // int[1024]
#define WS_ADJO   49792    // int[16384]  other-endpoint rank
#define WS_ADJE   66176    // int[16384]  (edge<<1)|sign_is_plus
#define WS_END    82560
#define WS_ZERO_BYTES ((size_t)WS_END * 4)

// ---------------------------------------------------------------- row dots
// one wave per row; rows [0,NN) = nodes, [NN, NN+EE) = edges
__global__ void k_rowdots(const float* __restrict__ xn, const float* __restrict__ xe,
                          const float* __restrict__ Wn0, const float* __restrict__ Wn1,
                          const float* __restrict__ We0, const float* __restrict__ We1,
                          float* __restrict__ wsf) {
    int w = (blockIdx.x * blockDim.x + threadIdx.x) >> 6;
    int lane = threadIdx.x & 63;
    if (w >= NN + EE) return;
    const float *x, *W0, *W1;
    float *t1, *sl;
    int r;
    if (w < NN) { r = w;      x = xn + (size_t)r * CN; W0 = Wn0; W1 = Wn1; t1 = wsf + WS_T1N; sl = wsf + WS_SLINN; }
    else        { r = w - NN; x = xe + (size_t)r * CE; W0 = We0; W1 = We1; t1 = wsf + WS_T1E; sl = wsf + WS_SLINE; }
    float4 xv = ((const float4*)x)[lane];
    float4 w0 = ((const float4*)W0)[lane];
    float4 w1 = ((const float4*)W1)[lane];
    float d0 = xv.x*w0.x + xv.y*w0.y + xv.z*w0.z + xv.w*w0.w;
    float d1 = xv.x*w1.x + xv.y*w1.y + xv.z*w1.z + xv.w*w1.w;
    #pragma unroll
    for (int o = 32; o > 0; o >>= 1) { d0 += __shfl_down(d0, o, 64); d1 += __shfl_down(d1, o, 64); }
    if (lane == 0) { t1[r] = d1; sl[r] = d0 + d1; }
}

// ------------------------------------------------------- conv-edge scatter
__global__ void k_agg(const int* __restrict__ ein, const float* __restrict__ ewn,
                      const int* __restrict__ eie, const float* __restrict__ ewe,
                      float* __restrict__ wsf) {
    int i = blockIdx.x * blockDim.x + threadIdx.x;
    if (i < MN) {
        int s = ein[i], d = ein[MN + i];
        atomicAdd(wsf + WS_AGGN + d, ewn[i] * wsf[WS_T1N + s]);
    }
    if (i < ME) {
        int s = eie[i], d = eie[ME + i];
        atomicAdd(wsf + WS_AGGE + d, ewe[i] * wsf[WS_T1E + s]);
    }
}

// ---------------------------------------------------------------- sigmoid
__global__ void k_score(const float* __restrict__ bn, const float* __restrict__ be,
                        float* __restrict__ wsf) {
    int i = blockIdx.x * blockDim.x + threadIdx.x;
    if (i < NN) {
        float z = wsf[WS_SLINN + i] - wsf[WS_AGGN + i] + bn[0];
        float s = 1.0f / (1.0f + expf(-z));
        wsf[WS_SCN + i] = s;
        wsf[WS_JOINT + i] = s;
    } else if (i < NN + EE) {
        int j = i - NN;
        float z = wsf[WS_SLINE + j] - wsf[WS_AGGE + j] + be[0];
        wsf[WS_SCE + j] = 1.0f / (1.0f + expf(-z));
    }
}

__global__ void k_joint(const int* __restrict__ ei, float* __restrict__ wsf) {
    int e = blockIdx.x * blockDim.x + threadIdx.x;
    if (e >= EE) return;
    float v = 0.125f * wsf[WS_SCE + e];
    atomicAdd(wsf + WS_JOINT + ei[e], v);
    atomicAdd(wsf + WS_JOINT + ei[EE + e], v);
}

// ------------------------------------------------------- top-K (single block)
__global__ __launch_bounds__(1024) void k_topk(float* __restrict__ wsf, int* __restrict__ wsi) {
    __shared__ unsigned long long keys[2048];
    __shared__ unsigned ids[1024];
    int t = threadIdx.x;
    wsi[WS_RANK + t] = -1;
    wsi[WS_RANK + t + 1024] = -1;
    for (int i = t; i < 2048; i += 1024) {
        float f = wsf[WS_JOINT + i];
        unsigned u = __float_as_uint(f);
        unsigned s = (u & 0x80000000u) ? ~u : (u | 0x80000000u);
        keys[i] = (((unsigned long long)(~s)) << 32) | (unsigned)i;  // asc sort => val desc, idx asc
    }
    __syncthreads();
    for (int k = 2; k <= 2048; k <<= 1) {
        for (int j = k >> 1; j >= 1; j >>= 1) {
            for (int i = t; i < 2048; i += 1024) {
                int ixj = i ^ j;
                if (ixj > i) {
                    bool up = ((i & k) == 0);
                    unsigned long long a = keys[i], b = keys[ixj];
                    if ((a > b) == up) { keys[i] = b; keys[ixj] = a; }
                }
            }
            __syncthreads();
        }
    }
    ids[t] = (unsigned)(keys[t] & 0xFFFFFFFFu);
    __syncthreads();
    for (int k = 2; k <= 1024; k <<= 1) {
        for (int j = k >> 1; j >= 1; j >>= 1) {
            int i = t, ixj = i ^ j;
            if (ixj > i) {
                bool up = ((i & k) == 0);
                unsigned a = ids[i], b = ids[ixj];
                if ((a > b) == up) { ids[i] = b; ids[ixj] = a; }
            }
            __syncthreads();
        }
    }
    wsi[WS_IDXK + t] = (int)ids[t];
    wsi[WS_RANK + (int)ids[t]] = t;
}

// ----------------------------- kept-edge pass: par_masked, L0 nnz, degrees
__global__ void k_build(const int* __restrict__ ei, int* __restrict__ wsi,
                        float* __restrict__ pm, float* __restrict__ L0) {
    int e = blockIdx.x * blockDim.x + threadIdx.x;
    if (e >= EE) return;
    int s = ei[e], d = ei[EE + e];
    int rs = wsi[WS_RANK + s], rd = wsi[WS_RANK + d];
    if (rs < 0 || rd < 0 || s == d) return;
    pm[(size_t)rs * EE + e] = -1.0f;
    pm[(size_t)rd * EE + e] =  1.0f;
    atomicAdd(wsi + WS_DEG + rs, 1);
    atomicAdd(wsi + WS_DEG + rd, 1);
    atomicAdd(&L0[(size_t)rs * KK + rs],  1.0f);
    atomicAdd(&L0[(size_t)rd * KK + rd],  1.0f);
    atomicAdd(&L0[(size_t)rs * KK + rd], -1.0f);
    atomicAdd(&L0[(size_t)rd * KK + rs], -1.0f);
}

// --------------------------------------------------------------- CSR scan
__global__ __launch_bounds__(1024) void k_scan(int* __restrict__ wsi) {
    __shared__ int s[1024];
    int t = threadIdx.x;
    int dg = wsi[WS_DEG + t];
    s[t] = dg;
    for (int off = 1; off < 1024; off <<= 1) {
        __syncthreads();
        int v = (t >= off) ? s[t - off] : 0;
        __syncthreads();
        s[t] += v;
    }
    __syncthreads();
    wsi[WS_OFFS + t] = s[t] - dg;
    wsi[WS_CUR  + t] = s[t] - dg;
    if (t == 1023) wsi[WS_OFFS + 1024] = s[1023];
}

__global__ void k_fill(const int* __restrict__ ei, int* __restrict__ wsi) {
    int e = blockIdx.x * blockDim.x + threadIdx.x;
    if (e >= EE) return;
    int s = ei[e], d = ei[EE + e];
    int rs = wsi[WS_RANK + s], rd = wsi[WS_RANK + d];
    if (rs < 0 || rd < 0 || s == d) return;
    int p = atomicAdd(wsi + WS_CUR + rs, 1);
    wsi[WS_ADJO + p] = rd;
    wsi[WS_ADJE + p] = (e << 1);        // sign -1 (src)
    int q = atomicAdd(wsi + WS_CUR + rd, 1);
    wsi[WS_ADJO + q] = rs;
    wsi[WS_ADJE + q] = (e << 1) | 1;    // sign +1 (dst)
}

// --------------------------------------------------- block reduce (16 waves)
__device__ __forceinline__ float block_reduce_sum(float val, float* red) {
    #pragma unroll
    for (int o = 32; o > 0; o >>= 1) val += __shfl_down(val, o, 64);
    int lane = threadIdx.x & 63, wid = threadIdx.x >> 6;
    if (lane == 0) red[wid] = val;
    __syncthreads();
    float r = 0.0f;
    if (threadIdx.x < 16) {
        r = red[threadIdx.x];
        #pragma unroll
        for (int o = 8; o > 0; o >>= 1) r += __shfl_down(r, o, 16);
        if (threadIdx.x == 0) red[0] = r;
    }
    __syncthreads();
    float out = red[0];
    __syncthreads();
    return out;
}

// ------------------------------------------- power iteration for lambda_max
// Worst-case adjacency fits in LDS entirely (2*EE entries); no global fallback.
#define ADJ_LDS (2 * EE)
#define DCAP 8
__global__ __launch_bounds__(1024) void k_power(const int* __restrict__ wsi, float* __restrict__ lam) {
    __shared__ float vbuf[2][1024];
    __shared__ float red[16];
    __shared__ int adjs[ADJ_LDS + DCAP];   // +DCAP pad: predicated preload may touch past end
    int t = threadIdx.x;
    int d  = wsi[WS_DEG + t];
    int o0 = wsi[WS_OFFS + t];
    int total = wsi[WS_OFFS + 1024];
    for (int i = t; i < total; i += 1024) adjs[i] = wsi[WS_ADJO + i];
    // pseudo-random init (all-ones is in ker(L0)!)
    unsigned h = (unsigned)t * 2654435761u + 911u;
    h ^= h >> 15; h *= 2246822519u; h ^= h >> 13;
    vbuf[0][t] = (float)(h & 0xFFFFu) * (1.0f / 65536.0f) - 0.5f;
    __syncthreads();
    // register-cache first DCAP adjacency entries (safe default 0)
    int aj[DCAP];
    #pragma unroll
    for (int j = 0; j < DCAP; ++j) aj[j] = (j < d) ? adjs[o0 + j] : 0;
    float* vc = vbuf[0];
    float* vn = vbuf[1];
    const int T = 96;   // multiple of 8 -> last iter normalized
    for (int iter = 0; iter < T; ++iter) {
        float acc = 0.0f;
        #pragma unroll
        for (int j = 0; j < DCAP; ++j) acc += (j < d) ? vc[aj[j]] : 0.0f;
        for (int i = o0 + DCAP; i < o0 + d; ++i) acc += vc[adjs[i]];  // rare tail (d > 8)
        float y = (float)d * vc[t] - acc;
        if ((iter & 7) == 7) {
            float n2 = block_reduce_sum(y * y, red);
            y *= (n2 > 0.0f) ? rsqrtf(n2) : 0.0f;
        }
        vn[t] = y;
        __syncthreads();
        float* tmp = vc; vc = vn; vn = tmp;
    }
    // Rayleigh quotient with normalized v (in vc)
    float acc = 0.0f;
    #pragma unroll
    for (int j = 0; j < DCAP; ++j) acc += (j < d) ? vc[aj[j]] : 0.0f;
    for (int i = o0 + DCAP; i < o0 + d; ++i) acc += vc[adjs[i]];
    float y = (float)d * vc[t] - acc;
    float rq = block_reduce_sum(vc[t] * y, red);
    if (t == 0) lam[0] = rq;
}

// --------------------------------------------------------------- L0 scale
__global__ void k_scaleL0(float* __restrict__ L0, const float* __restrict__ lam) {
    int i = blockIdx.x * blockDim.x + threadIdx.x;
    if (i >= KK * KK) return;
    L0[i] *= 2.0f / lam[0];
}

// ------------------------------------------------------------- L1 scatter
__global__ void k_L1(const int* __restrict__ wsi, const float* __restrict__ lam,
                     float* __restrict__ L1) {
    int r = blockIdx.x * blockDim.x + threadIdx.x;
    if (r >= KK) return;
    int o0 = wsi[WS_OFFS + r], o1 = wsi[WS_OFFS + r + 1];
    float sc = 2.0f / lam[0];
    for (int i = o0; i < o1; ++i) {
        int eiv = wsi[WS_ADJE + i];
        int e = eiv >> 1;
        float si = (eiv & 1) ? 1.0f : -1.0f;
        for (int j = o0; j < o1; ++j) {
            int ejv = wsi[WS_ADJE + j];
            int f = ejv >> 1;
            float sj = (ejv & 1) ? 1.0f : -1.0f;
            atomicAdd(&L1[(size_t)e * EE + f], si * sj * sc);
        }
    }
}

// --------------------------------------------------------- feature outputs
__global__ void k_gather_nodes(const float* __restrict__ xn, const float* __restrict__ xn0,
                               const float* __restrict__ wsf, const int* __restrict__ wsi,
                               float* __restrict__ out_xn, float* __restrict__ out_xn0) {
    int r = blockIdx.x, c = threadIdx.x;
    int src = wsi[WS_IDXK + r];
    float sc = wsf[WS_SCN + src];
    out_xn [(size_t)r * CN + c] = xn [(size_t)src * CN + c] * sc;
    out_xn0[(size_t)r * CN + c] = xn0[(size_t)src * CN + c];
}

__global__ void k_edges_out(const float* __restrict__ xe, const float* __restrict__ xe0,
                            const float* __restrict__ wsf, const int* __restrict__ wsi,
                            const int* __restrict__ ei,
                            float* __restrict__ out_xe, float* __restrict__ out_xe0) {
    int e = blockIdx.x, c = threadIdx.x;
    int s = ei[e], d = ei[EE + e];
    if (wsi[WS_RANK + s] < 0 || wsi[WS_RANK + d] < 0) return;  // row stays zero
    float sc = wsf[WS_SCE + e];
    out_xe [(size_t)e * CE + c] = xe [(size_t)e * CE + c] * sc;
    out_xe0[(size_t)e * CE + c] = xe0[(size_t)e * CE + c];
}

extern "C" void kernel_launch(void* const* d_in, const int* in_sizes, int n_in,
                              void* d_out, int out_size, void* d_ws, size_t ws_size,
                              hipStream_t stream) {
    const float* x_n  = (const float*)d_in[0];
    const int*   ei_n = (const int*)  d_in[1];
    const float* ew_n = (const float*)d_in[2];
    const float* x_e  = (const float*)d_in[3];
    const int*   ei_e = (const int*)  d_in[4];
    const float* ew_e = (const float*)d_in[5];
    const int*   ei   = (const int*)  d_in[6];
    const float* x_n0 = (const float*)d_in[9];
    const float* x_e0 = (const float*)d_in[10];
    const float* Wn0  = (const float*)d_in[11];
    const float* Wn1  = (const float*)d_in[12];
    const float* bn   = (const float*)d_in[13];
    const float* We0  = (const float*)d_in[14];
    const float* We1  = (const float*)d_in[15];
    const float* be   = (const float*)d_in[16];

    float* out = (float*)d_out;
    float* wsf = (float*)d_ws;
    int*   wsi = (int*)d_ws;

    hipMemsetAsync(d_out, 0, (size_t)out_size * sizeof(float), stream);
    hipMemsetAsync(d_ws, 0, WS_ZERO_BYTES, stream);

    k_rowdots<<<(NN + EE) / 4, 256, 0, stream>>>(x_n, x_e, Wn0, Wn1, We0, We1, wsf);
    k_agg<<<ME / 256, 256, 0, stream>>>(ei_n, ew_n, ei_e, ew_e, wsf);
    k_score<<<(NN + EE) / 256, 256, 0, stream>>>(bn, be, wsf);
    k_joint<<<EE / 256, 256, 0, stream>>>(ei, wsf);
    k_topk<<<1, 1024, 0, stream>>>(wsf, wsi);
    k_build<<<EE / 256, 256, 0, stream>>>(ei, wsi, out + OUT_PM, out + OUT_L0);
    k_scan<<<1, 1024, 0, stream>>>(wsi);
    k_fill<<<EE / 256, 256, 0, stream>>>(ei, wsi);
    k_power<<<1, 1024, 0, stream>>>(wsi, wsf + WS_LAM);
    k_scaleL0<<<(KK * KK) / 256, 256, 0, stream>>>(out + OUT_L0, wsf + WS_LAM);
    k_L1<<<KK / 256, 256, 0, stream>>>(wsi, wsf + WS_LAM, out + OUT_L1);
    k_gather_nodes<<<KK, 256, 0, stream>>>(x_n, x_n0, wsf, wsi, out + OUT_XN, out + OUT_XN0);
    k_edges_out<<<EE, 256, 0, stream>>>(x_e, x_e0, wsf, wsi, ei, out + OUT_XE, out + OUT_XE0);
}